// Round 4
// baseline (129.581 us; speedup 1.0000x reference)
//
#include <hip/hip_runtime.h>
#include <hip/hip_bf16.h>

typedef short bf16x8 __attribute__((ext_vector_type(8)));
typedef float f32x4 __attribute__((ext_vector_type(4)));

#define N_NODES 1024
#define FDIM 64
#define NG 32   // B * Tp = 2 * 16
#define LOG2E 1.44269504088896f

// ---------------- K0: expand adjacency into additive bf16 mask ----------------
__global__ __launch_bounds__(256) void k_maskf(const int* __restrict__ adj,
                                               __hip_bfloat16* __restrict__ Madd) {
    int w = blockIdx.x * 256 + threadIdx.x;      // 32768 threads, 32 els each
    const int* p = adj + (size_t)w * 32;
    union { bf16x8 v[4]; __hip_bfloat16 hh[32]; } u;
#pragma unroll
    for (int b = 0; b < 32; b++)
        u.hh[b] = __float2bfloat16(p[b] > 0 ? 0.f : -2048.f);
    bf16x8* dst = (bf16x8*)(Madd + (size_t)w * 32);
#pragma unroll
    for (int q = 0; q < 4; q++) dst[q] = u.v[q];
}

// ---------------- K1: layer-1 projection + score vectors (×log2e) ----------------
__global__ __launch_bounds__(256) void k_proj1(const float* __restrict__ x,
                                               const float* __restrict__ Wh,
                                               const float* __restrict__ ah,
                                               __hip_bfloat16* __restrict__ H1T,
                                               float* __restrict__ F1,
                                               float* __restrict__ F2) {
    __shared__ float xs[64][68];
    __shared__ float ws[64][64];
    const int t = threadIdx.x;
    const int nt = blockIdx.x, g = blockIdx.y, h = blockIdx.z;
    const int n0 = nt * 64;
    const int b = g >> 4, tstep = g & 15;
    const int r = t >> 2, cq = t & 3;

    const float* xrow = x + (((size_t)(b * 17 + tstep) * N_NODES + n0 + r) * FDIM);
    const float4* xsrc = (const float4*)(xrow + cq * 16);
#pragma unroll
    for (int q = 0; q < 4; q++) *(float4*)&xs[r][cq * 16 + q * 4] = xsrc[q];
    const float4* wsrc = (const float4*)(Wh + (size_t)h * 4096 + (size_t)r * 64 + cq * 16);
#pragma unroll
    for (int q = 0; q < 4; q++) *(float4*)&ws[r][cq * 16 + q * 4] = wsrc[q];
    __syncthreads();

    float acc[16];
#pragma unroll
    for (int c = 0; c < 16; c++) acc[c] = 0.f;
    for (int k = 0; k < 64; k++) {
        float a = xs[r][k];
        const float* wr = &ws[k][cq * 16];
#pragma unroll
        for (int c = 0; c < 16; c++) acc[c] = fmaf(a, wr[c], acc[c]);
    }

    const float* a1 = ah + h * 128;
    float p1 = 0.f, p2 = 0.f;
#pragma unroll
    for (int c = 0; c < 16; c++) {
        p1 = fmaf(acc[c], a1[cq * 16 + c], p1);
        p2 = fmaf(acc[c], a1[64 + cq * 16 + c], p2);
    }
    p1 += __shfl_xor(p1, 1); p1 += __shfl_xor(p1, 2);
    p2 += __shfl_xor(p2, 1); p2 += __shfl_xor(p2, 2);
    const int n = n0 + r;
    const size_t gh = (size_t)h * NG + g;
    if (cq == 0) {
        F1[gh * N_NODES + n] = p1 * LOG2E;
        F2[gh * N_NODES + n] = p2 * LOG2E;
    }
    __hip_bfloat16* Hb = H1T + gh * FDIM * N_NODES;
#pragma unroll
    for (int c = 0; c < 16; c++)
        Hb[(size_t)(cq * 16 + c) * N_NODES + n] = __float2bfloat16(acc[c]);
}

// ---------------- fused masked attention ----------------
// 128 rows/block, 8 waves x 16 rows; j-tile 256 double-buffered in LDS with
// XOR-swizzled 16B units (conflict-free b128 read+write); additive-mask +
// exp2 score path; row-sum via ones-MFMA; 1 barrier per j-tile.
template<int CONCAT>
__global__ __launch_bounds__(512, 4) void k_attn(
    const __hip_bfloat16* __restrict__ HT,   // [G][64 f][1024 n] bf16
    const float* __restrict__ F1,            // [G][1024] (×log2e)
    const float* __restrict__ F2,
    const __hip_bfloat16* __restrict__ Madd, // [1024][1024] additive mask
    __hip_bfloat16* __restrict__ HC,         // concat out (CONCAT=1)
    float* __restrict__ out)                 // final out (CONCAT=0)
{
    __shared__ __hip_bfloat16 vt[2][64][256]; // linear rows; unit-XOR swizzle
    __shared__ float f2s[N_NODES];
    const int t = threadIdx.x;
    const int nb = blockIdx.x, g = blockIdx.y, h = blockIdx.z;
    const int i0 = nb * 128;
    const size_t gidx = CONCAT ? ((size_t)h * NG + g) : (size_t)g;

    ((float2*)f2s)[t] = ((const float2*)(F2 + gidx * N_NODES))[t];

    const int wv = t >> 6, ln = t & 63;
    const int li = ln & 15, grp = ln >> 4, jb = grp * 8;
    const int lx = li & 7;
    const int il = wv * 16 + li;
    const float f1v = F1[gidx * N_NODES + i0 + il];

    const __hip_bfloat16* Hg = HT + gidx * (size_t)(FDIM * N_NODES);
    const int srow = wv * 8 + (ln >> 3);          // staging row (f)
    const int swu = (ln & 7) ^ (srow & 7);        // swizzled low-3 unit for writes
    const __hip_bfloat16* srcb = Hg + (size_t)srow * N_NODES + (ln & 7) * 8;
    const __hip_bfloat16* Mrow = Madd + (size_t)(i0 + il) * N_NODES + jb;

    f32x4 acc[4], acc5;
#pragma unroll
    for (int q = 0; q < 4; q++) acc[q] = (f32x4){0.f, 0.f, 0.f, 0.f};
    acc5 = (f32x4){0.f, 0.f, 0.f, 0.f};

    union { bf16x8 v; short s[8]; } onesu;
#pragma unroll
    for (int q = 0; q < 8; q++) onesu.s[q] = (short)0x3F80;  // bf16 1.0
    const bf16x8 ones = onesu.v;

    bf16x8 stg[4];
#pragma unroll
    for (int k2 = 0; k2 < 4; k2++) stg[k2] = *(const bf16x8*)(srcb + k2 * 64);
#pragma unroll
    for (int k2 = 0; k2 < 4; k2++)
        *(bf16x8*)&vt[0][srow][(k2 * 8 + swu) * 8] = stg[k2];
    bf16x8 mreg = *(const bf16x8*)(Mrow);

    for (int jt = 0; jt < 4; jt++) {
        if (jt < 3) {                         // issue next tile's global loads
#pragma unroll
            for (int k2 = 0; k2 < 4; k2++)
                stg[k2] = *(const bf16x8*)(srcb + (jt + 1) * 256 + k2 * 64);
        }
        __syncthreads();                      // vt[jt&1] fully written

#pragma unroll
        for (int jc = 0; jc < 8; jc++) {
            union { bf16x8 v; unsigned u[4]; } mc;
            mc.v = mreg;
            if (!(jt == 3 && jc == 7))
                mreg = *(const bf16x8*)(Mrow + jt * 256 + jc * 32 + 32);

            const float* f2p = &f2s[jt * 256 + jc * 32 + jb];
            float4 fa = *(const float4*)f2p;
            float4 fb = *(const float4*)(f2p + 4);
            float f2a[8] = {fa.x, fa.y, fa.z, fa.w, fb.x, fb.y, fb.z, fb.w};
            union { bf16x8 v; __hip_bfloat16 hh[8]; } afr;
#pragma unroll
            for (int d = 0; d < 4; d++) {
                float mlo = __uint_as_float(mc.u[d] << 16);
                float mhi = __uint_as_float(mc.u[d] & 0xffff0000u);
                float s0 = f1v + f2a[2 * d] + mlo;       // v_add3
                float s1 = f1v + f2a[2 * d + 1] + mhi;
                s0 = fmaxf(s0, 0.2f * s0);               // LeakyReLU
                s1 = fmaxf(s1, 0.2f * s1);
                float p0 = __builtin_amdgcn_exp2f(s0);
                float p1 = __builtin_amdgcn_exp2f(s1);
                afr.hh[2 * d]     = __float2bfloat16(p0);
                afr.hh[2 * d + 1] = __float2bfloat16(p1);
            }
            // swizzled B-frag read: unit = jc*4+grp, low3 XOR li&7
            const int ub = (jc >> 1) * 8 + (((jc & 1) * 4 + grp) ^ lx);
#pragma unroll
            for (int q = 0; q < 4; q++) {
                bf16x8 bfr = *(const bf16x8*)&vt[jt & 1][q * 16 + li][ub * 8];
                acc[q] = __builtin_amdgcn_mfma_f32_16x16x32_bf16(afr.v, bfr, acc[q], 0, 0, 0);
            }
            acc5 = __builtin_amdgcn_mfma_f32_16x16x32_bf16(afr.v, ones, acc5, 0, 0, 0);
        }

        if (jt < 3) {                         // write next tile (other buffer)
#pragma unroll
            for (int k2 = 0; k2 < 4; k2++)
                *(bf16x8*)&vt[(jt + 1) & 1][srow][(k2 * 8 + swu) * 8] = stg[k2];
        }
    }

    float rin[4];
#pragma unroll
    for (int r2 = 0; r2 < 4; r2++) rin[r2] = 1.0f / acc5[r2];

    if (CONCAT) {
        __hip_bfloat16* HCg = HC + (size_t)g * N_NODES * 256 + h * 64;
#pragma unroll
        for (int q = 0; q < 4; q++)
#pragma unroll
            for (int r2 = 0; r2 < 4; r2++) {
                int irow = wv * 16 + grp * 4 + r2;
                float v = acc[q][r2] * rin[r2];
                v = v > 0.f ? v : expm1f(v); // ELU
                HCg[(size_t)(i0 + irow) * 256 + q * 16 + li] = __float2bfloat16(v);
            }
    } else {
        float* og = out + (size_t)g * N_NODES * FDIM;
#pragma unroll
        for (int q = 0; q < 4; q++)
#pragma unroll
            for (int r2 = 0; r2 < 4; r2++) {
                int irow = wv * 16 + grp * 4 + r2;
                float v = acc[q][r2] * rin[r2];
                og[(size_t)(i0 + irow) * FDIM + q * 16 + li] = v > 0.f ? v : 0.f;
            }
    }
}

// ---------------- K3: layer-2 projection + score vectors ----------------
__global__ __launch_bounds__(256) void k_proj2(const __hip_bfloat16* __restrict__ HC,
                                               const float* __restrict__ Wo,
                                               const float* __restrict__ ao,
                                               __hip_bfloat16* __restrict__ H2T,
                                               float* __restrict__ F1b,
                                               float* __restrict__ F2b) {
    __shared__ float xs[64][68];
    __shared__ float ws[64][64];
    const int t = threadIdx.x;
    const int nt = blockIdx.x, g = blockIdx.y;
    const int n0 = nt * 64;
    const int r = t >> 2, cq = t & 3;
    float acc[16];
#pragma unroll
    for (int c = 0; c < 16; c++) acc[c] = 0.f;

    for (int k0 = 0; k0 < 256; k0 += 64) {
        const __hip_bfloat16* src = HC + ((size_t)g * N_NODES + n0 + r) * 256 + k0 + cq * 16;
        union { bf16x8 v; __hip_bfloat16 hh[8]; } u0, u1;
        u0.v = *(const bf16x8*)(src);
        u1.v = *(const bf16x8*)(src + 8);
#pragma unroll
        for (int c = 0; c < 8; c++) {
            xs[r][cq * 16 + c] = __bfloat162float(u0.hh[c]);
            xs[r][cq * 16 + 8 + c] = __bfloat162float(u1.hh[c]);
        }
        const float4* wsrc = (const float4*)(Wo + (size_t)(k0 + r) * 64 + cq * 16);
#pragma unroll
        for (int q = 0; q < 4; q++) *(float4*)&ws[r][cq * 16 + q * 4] = wsrc[q];
        __syncthreads();
        for (int k = 0; k < 64; k++) {
            float a = xs[r][k];
            const float* wr = &ws[k][cq * 16];
#pragma unroll
            for (int c = 0; c < 16; c++) acc[c] = fmaf(a, wr[c], acc[c]);
        }
        __syncthreads();
    }

    float p1 = 0.f, p2 = 0.f;
#pragma unroll
    for (int c = 0; c < 16; c++) {
        p1 = fmaf(acc[c], ao[cq * 16 + c], p1);
        p2 = fmaf(acc[c], ao[64 + cq * 16 + c], p2);
    }
    p1 += __shfl_xor(p1, 1); p1 += __shfl_xor(p1, 2);
    p2 += __shfl_xor(p2, 1); p2 += __shfl_xor(p2, 2);
    const int n = n0 + r;
    if (cq == 0) {
        F1b[(size_t)g * N_NODES + n] = p1 * LOG2E;
        F2b[(size_t)g * N_NODES + n] = p2 * LOG2E;
    }
    __hip_bfloat16* Hb = H2T + (size_t)g * FDIM * N_NODES;
#pragma unroll
    for (int c = 0; c < 16; c++)
        Hb[(size_t)(cq * 16 + c) * N_NODES + n] = __float2bfloat16(acc[c]);
}

extern "C" void kernel_launch(void* const* d_in, const int* in_sizes, int n_in,
                              void* d_out, int out_size, void* d_ws, size_t ws_size,
                              hipStream_t stream) {
    const float* x  = (const float*)d_in[0];
    const int* adj  = (const int*)d_in[1];
    const float* Wh = (const float*)d_in[2];
    const float* ah = (const float*)d_in[3];
    const float* Wo = (const float*)d_in[4];
    const float* ao = (const float*)d_in[5];

    char* ws = (char*)d_ws;
    __hip_bfloat16* Madd = (__hip_bfloat16*)(ws);                  // 2 MB
    float* F1  = (float*)(ws + 2097152);                           // 512 KB
    float* F2  = (float*)(ws + 2621440);                           // 512 KB
    float* F1b = (float*)(ws + 3145728);                           // 128 KB
    float* F2b = (float*)(ws + 3276800);                           // 128 KB
    __hip_bfloat16* H1T = (__hip_bfloat16*)(ws + 3407872);             // 16 MB
    __hip_bfloat16* HC  = (__hip_bfloat16*)(ws + 3407872 + 16777216);  // 16 MB
    __hip_bfloat16* H2T = (__hip_bfloat16*)(ws + 3407872 + 33554432);  //  4 MB
    float* out = (float*)d_out;

    k_maskf  <<<dim3(128),       dim3(256), 0, stream>>>(adj, Madd);
    k_proj1  <<<dim3(16, 32, 4), dim3(256), 0, stream>>>(x, Wh, ah, H1T, F1, F2);
    k_attn<1><<<dim3(8, 32, 4),  dim3(512), 0, stream>>>(H1T, F1, F2, Madd, HC, nullptr);
    k_proj2  <<<dim3(16, 32),    dim3(256), 0, stream>>>(HC, Wo, ao, H2T, F1b, F2b);
    k_attn<0><<<dim3(8, 32, 1),  dim3(512), 0, stream>>>(H2T, F1b, F2b, Madd, nullptr, out);
}